// Round 2
// baseline (668.076 us; speedup 1.0000x reference)
//
#include <hip/hip_runtime.h>
#include <hip/hip_bf16.h>
#include <stdint.h>

// ---------------------------------------------------------------------------
// TFEfficientFormerSelfAttention  (B=256, S=256, DIM=448, H=8, KD=32, EKD=128)
// Round 2: attention rewritten — no Q/K/V LDS staging (global coalesced frag
// reads, L1/L2-resident), bias as MFMA C-in, SCALE folded into Q, double-
// buffered P in LDS only (34KB -> 4 blocks/CU), query-pair iteration halves
// V traffic and barrier count, PV computes ctx^T for 8B vectorized stores.
// MFMA fragment layouts (verified m89/m91):
//   A: row=l&15, k=(l>>4)*8+j ; B: col=l&15, k=(l>>4)*8+j ;
//   D: col=l&15, row=(l>>4)*4+r.
// ---------------------------------------------------------------------------

typedef __attribute__((ext_vector_type(4))) float f32x4;
typedef __attribute__((ext_vector_type(8))) short short8;
typedef __attribute__((ext_vector_type(4))) unsigned short u16x4;

#define DEVINL static __device__ __forceinline__

DEVINL unsigned short f2bf(float f) {
  unsigned u = __float_as_uint(f);
  return (unsigned short)((u + 0x7FFFu + ((u >> 16) & 1u)) >> 16);
}
DEVINL float bf2f(short s) {
  return __uint_as_float(((unsigned)(unsigned short)s) << 16);
}

DEVINL void gload_lds16(const void* g, void* l) {
  __builtin_amdgcn_global_load_lds((const __attribute__((address_space(1))) void*)g,
                                   (__attribute__((address_space(3))) void*)l,
                                   16, 0, 0);
}

#define SCALE 0.17677669529663687f

// ---------------- workspace layout (bytes) ----------------
#define WS_XB    ((size_t)0)
#define WS_CTX   ((size_t)0)
#define WS_WQT   ((size_t)134217728)   // 1536x448 bf16
#define WS_WPT   ((size_t)135593984)   // 512x1024 bf16 (padded rows 448..511 = 0)
#define WS_QW    ((size_t)136642560)   // [2048][256][32] bf16 (pre-scaled by SCALE)
#define WS_KW    ((size_t)170196992)   // [2048][256][32] bf16
#define WS_VT    ((size_t)203751424)   // [2048][128][264] bf16 (s padded 256->264)
#define WS_BIAS  ((size_t)342163456)   // [8][256][256] f32

// ---------------- prep kernels ----------------

__global__ void k_convert_x(const float* __restrict__ x, short* __restrict__ xb) {
  const size_t i = (size_t)blockIdx.x * blockDim.x + threadIdx.x;  // 8 elems each
  const f32x4* src = (const f32x4*)x + i * 2;
  f32x4 a = src[0], b = src[1];
  short8 o;
#pragma unroll
  for (int t = 0; t < 4; ++t) o[t] = (short)f2bf(a[t]);
#pragma unroll
  for (int t = 0; t < 4; ++t) o[4 + t] = (short)f2bf(b[t]);
  ((short8*)xb)[i] = o;
}

__global__ void k_transpose_bf16(const float* __restrict__ in, short* __restrict__ out,
                                 int K, int N, int total) {
  const int idx = blockIdx.x * blockDim.x + threadIdx.x;
  if (idx >= total) return;
  const int n = idx / K, k = idx - n * K;
  const float v = (n < N) ? in[(size_t)k * N + n] : 0.0f;
  out[idx] = (short)f2bf(v);
}

__global__ void k_bias_gather(const float* __restrict__ biases, const int* __restrict__ idxs,
                              float* __restrict__ outb, int n_off) {
  const int i = blockIdx.x * blockDim.x + threadIdx.x;  // < 524288
  const int h = i >> 16, p = i & 65535;
  outb[i] = biases[h * n_off + idxs[p]];
}

// ---------------- shared 128x128 GEMM mainloop (m97 structure) ----------------

template <int KSTEPS, int LDA, int LDB>
DEVINL void gemm128_body(const short* __restrict__ A, const short* __restrict__ B,
                         short* Asm, short* Bsm, int m0, int n0, int tid,
                         f32x4 acc[4][4]) {
  const int lane = tid & 63, wave = tid >> 6;
  const int l15 = lane & 15, g = lane >> 4;
  const int wm = wave >> 1, wn = wave & 1;
  const int srow = wave * 32 + (lane >> 2);
  const int scol = (lane & 3) * 8;
  for (int ks = 0; ks < KSTEPS; ++ks) {
    const int k0 = ks * 32;
#pragma unroll
    for (int c = 0; c < 2; ++c) {
      gload_lds16(A + (size_t)(m0 + srow + c * 16) * LDA + k0 + scol,
                  Asm + wave * 1024 + c * 512);
      gload_lds16(B + (size_t)(n0 + srow + c * 16) * LDB + k0 + scol,
                  Bsm + wave * 1024 + c * 512);
    }
    __syncthreads();
    short8 a[4], b[4];
#pragma unroll
    for (int i = 0; i < 4; ++i)
      a[i] = *(const short8*)(Asm + (wm * 64 + i * 16 + l15) * 32 + g * 8);
#pragma unroll
    for (int j = 0; j < 4; ++j)
      b[j] = *(const short8*)(Bsm + (wn * 64 + j * 16 + l15) * 32 + g * 8);
#pragma unroll
    for (int i = 0; i < 4; ++i)
#pragma unroll
      for (int j = 0; j < 4; ++j)
        acc[i][j] = __builtin_amdgcn_mfma_f32_16x16x32_bf16(a[i], b[j], acc[i][j], 0, 0, 0);
    __syncthreads();
  }
}

// ---------------- QKV GEMM: Xb[65536][448] @ Wt^T -> scatter Q/K/Vt ----------------

__global__ __launch_bounds__(256) void k_qkv_gemm(
    const short* __restrict__ Xb, const short* __restrict__ Wt,
    const float* __restrict__ qkvb,
    short* __restrict__ Qw, short* __restrict__ Kw, short* __restrict__ Vt) {
  __shared__ short Asm[4096], Bsm[4096];
  const int tid = threadIdx.x;
  const int m0 = blockIdx.x * 128, n0 = blockIdx.y * 128;
  f32x4 acc[4][4];
#pragma unroll
  for (int i = 0; i < 4; ++i)
#pragma unroll
    for (int j = 0; j < 4; ++j) acc[i][j] = (f32x4){0.f, 0.f, 0.f, 0.f};

  gemm128_body<14, 448, 448>(Xb, Wt, Asm, Bsm, m0, n0, tid, acc);

  const int lane = tid & 63, wave = tid >> 6;
  const int l15 = lane & 15, g = lane >> 4;
  const int wm = wave >> 1, wn = wave & 1;
#pragma unroll
  for (int i = 0; i < 4; ++i) {
    const int mb = m0 + wm * 64 + i * 16 + g * 4;  // 4 consecutive rows mb..mb+3
    const int bb = mb >> 8, s0 = mb & 255;
#pragma unroll
    for (int j = 0; j < 4; ++j) {
      const int n = n0 + wn * 64 + j * 16 + l15;
      const float bv = qkvb[n];
      const int h = n / 192;
      const int c = n - h * 192;
      const int bh = bb * 8 + h;
      if (c >= 64) {
        const int e = c - 64;
        u16x4 pk;
#pragma unroll
        for (int r = 0; r < 4; ++r) pk[r] = f2bf(acc[i][j][r] + bv);
        *(u16x4*)(Vt + (size_t)bh * 33792 + e * 264 + s0) = pk;  // 8B store
      } else {
        short* dst = (c < 32) ? Qw : Kw;
        const float sc = (c < 32) ? SCALE : 1.0f;   // fold softmax scale into Q
        const int d = c & 31;
        const size_t base = ((size_t)bh * 256 + s0) * 32 + d;
#pragma unroll
        for (int r = 0; r < 4; ++r)
          dst[base + (size_t)r * 32] = (short)f2bf((acc[i][j][r] + bv) * sc);
      }
    }
  }
}

// ---------------- fused attention per (b,h) ----------------
// 256 threads (4 waves), 4 blocks/CU. LDS: P double-buffer only (~34KB).
// Per query-pair (64 rows): score(bias C-in) -> softmax -> PV(ctx^T).

__global__ __launch_bounds__(256, 4) void k_attn(
    const short* __restrict__ Qw, const short* __restrict__ Kw,
    const short* __restrict__ Vt, const float* __restrict__ Bias,
    short* __restrict__ CTX) {
  __shared__ short Ps[2][32 * 264];
  __shared__ float rinv[2][32];

  const int tid = threadIdx.x, lane = tid & 63, wave = tid >> 6;  // 4 waves
  const int l15 = lane & 15, g = lane >> 4;
  const int bh = blockIdx.x;
  const int b = bh >> 3, h = bh & 7;  // consecutive blocks vary h -> per-XCD bias locality

  const short* Qb = Qw + (size_t)bh * 8192;
  const short* Kb = Kw + (size_t)bh * 8192;
  const short* Vb = Vt + (size_t)bh * 33792;
  const float* biasH = Bias + (size_t)h * 65536;

  for (int pair = 0; pair < 4; ++pair) {
    // ---- scores for 2 query-blocks (u=0,1); wave covers keys [wave*64, +64) ----
    short8 bk[4];
#pragma unroll
    for (int fj = 0; fj < 4; ++fj)
      bk[fj] = *(const short8*)(Kb + (wave * 64 + fj * 16 + l15) * 32 + g * 8);

#pragma unroll
    for (int u = 0; u < 2; ++u) {
      const int q0 = pair * 64 + u * 32;
      short8 aq[2];
#pragma unroll
      for (int i = 0; i < 2; ++i)
        aq[i] = *(const short8*)(Qb + (q0 + i * 16 + l15) * 32 + g * 8);
#pragma unroll
      for (int fj = 0; fj < 4; ++fj) {
        const int kk = wave * 64 + fj * 16 + l15;
#pragma unroll
        for (int i = 0; i < 2; ++i) {
          f32x4 acc;
#pragma unroll
          for (int r = 0; r < 4; ++r)
            acc[r] = biasH[(q0 + i * 16 + g * 4 + r) * 256 + kk];  // bias = C-in
          acc = __builtin_amdgcn_mfma_f32_16x16x32_bf16(aq[i], bk[fj], acc, 0, 0, 0);
#pragma unroll
          for (int r = 0; r < 4; ++r)
            Ps[u][(i * 16 + g * 4 + r) * 264 + kk] = (short)f2bf(acc[r]);
        }
      }
    }
    __syncthreads();  // B1

    // ---- softmax: 256 threads = 32 rows x 8 parts (32 values each), both bufs ----
    {
      const int r = tid >> 3, part = tid & 7;
#pragma unroll
      for (int u = 0; u < 2; ++u) {
        short* rowp = &Ps[u][r * 264 + part * 32];
        float v[32];
#pragma unroll
        for (int c = 0; c < 4; ++c) {
          short8 x = ((const short8*)rowp)[c];
#pragma unroll
          for (int t = 0; t < 8; ++t) v[c * 8 + t] = bf2f(x[t]);
        }
        float mx = v[0];
#pragma unroll
        for (int t = 1; t < 32; ++t) mx = fmaxf(mx, v[t]);
#pragma unroll
        for (int d = 1; d < 8; d <<= 1) mx = fmaxf(mx, __shfl_xor(mx, d));
        float sum = 0.f;
#pragma unroll
        for (int t = 0; t < 32; ++t) { v[t] = __expf(v[t] - mx); sum += v[t]; }
#pragma unroll
        for (int d = 1; d < 8; d <<= 1) sum += __shfl_xor(sum, d);
#pragma unroll
        for (int c = 0; c < 4; ++c) {
          short8 o;
#pragma unroll
          for (int t = 0; t < 8; ++t) o[t] = (short)f2bf(v[c * 8 + t]);
          ((short8*)rowp)[c] = o;
        }
        if (part == 0) rinv[u][r] = 1.0f / sum;
      }
    }
    __syncthreads();  // B2

    // ---- PV (ctx^T): A=V^T rows e, B=P cols q. Wave covers e [wave*32, +32) ----
    {
      f32x4 cacc[2][2][2];  // [u][et][qt]
#pragma unroll
      for (int u = 0; u < 2; ++u)
#pragma unroll
        for (int et = 0; et < 2; ++et)
#pragma unroll
          for (int qt = 0; qt < 2; ++qt) cacc[u][et][qt] = (f32x4){0.f, 0.f, 0.f, 0.f};

#pragma unroll
      for (int ks = 0; ks < 8; ++ks) {
        short8 av[2];
#pragma unroll
        for (int et = 0; et < 2; ++et)
          av[et] = *(const short8*)(Vb + (wave * 32 + et * 16 + l15) * 264 + ks * 32 + g * 8);
#pragma unroll
        for (int u = 0; u < 2; ++u)
#pragma unroll
          for (int qt = 0; qt < 2; ++qt) {
            const short8 bp = *(const short8*)&Ps[u][(qt * 16 + l15) * 264 + ks * 32 + g * 8];
#pragma unroll
            for (int et = 0; et < 2; ++et)
              cacc[u][et][qt] = __builtin_amdgcn_mfma_f32_16x16x32_bf16(av[et], bp, cacc[u][et][qt], 0, 0, 0);
          }
      }

#pragma unroll
      for (int u = 0; u < 2; ++u)
#pragma unroll
        for (int qt = 0; qt < 2; ++qt) {
          const int s = pair * 64 + u * 32 + qt * 16 + l15;
          const float rv = rinv[u][qt * 16 + l15];
#pragma unroll
          for (int et = 0; et < 2; ++et) {
            u16x4 pk;
#pragma unroll
            for (int r = 0; r < 4; ++r) pk[r] = f2bf(cacc[u][et][qt][r] * rv);
            *(u16x4*)(CTX + ((size_t)b * 256 + s) * 1024 + h * 128 + wave * 32 + et * 16 + g * 4) = pk;
          }
        }
    }
    __syncthreads();  // B3: protect Ps before next pair's score writes
  }
}

// ---------------- proj GEMM: CTX[65536][1024] @ WptT -> out f32 ----------------

__global__ __launch_bounds__(256) void k_proj_gemm(
    const short* __restrict__ CTX, const short* __restrict__ Wpt,
    const float* __restrict__ projb, float* __restrict__ out) {
  __shared__ short Asm[4096], Bsm[4096];
  const int tid = threadIdx.x;
  const int m0 = blockIdx.x * 128, n0 = blockIdx.y * 128;
  f32x4 acc[4][4];
#pragma unroll
  for (int i = 0; i < 4; ++i)
#pragma unroll
    for (int j = 0; j < 4; ++j) acc[i][j] = (f32x4){0.f, 0.f, 0.f, 0.f};

  gemm128_body<32, 1024, 1024>(CTX, Wpt, Asm, Bsm, m0, n0, tid, acc);

  const int lane = tid & 63, wave = tid >> 6;
  const int l15 = lane & 15, g = lane >> 4;
  const int wm = wave >> 1, wn = wave & 1;
#pragma unroll
  for (int i = 0; i < 4; ++i) {
    const int mb = m0 + wm * 64 + i * 16 + g * 4;
#pragma unroll
    for (int j = 0; j < 4; ++j) {
      const int n = n0 + wn * 64 + j * 16 + l15;
      if (n < 448) {
        const float bv = projb[n];
#pragma unroll
        for (int r = 0; r < 4; ++r)
          out[(size_t)(mb + r) * 448 + n] = acc[i][j][r] + bv;
      }
    }
  }
}

// ---------------- launch ----------------

extern "C" void kernel_launch(void* const* d_in, const int* in_sizes, int n_in,
                              void* d_out, int out_size, void* d_ws, size_t ws_size,
                              hipStream_t stream) {
  const float* X      = (const float*)d_in[0];
  const float* qkv_w  = (const float*)d_in[1];
  const float* qkv_b  = (const float*)d_in[2];
  const float* proj_w = (const float*)d_in[3];
  const float* proj_b = (const float*)d_in[4];
  const float* att_b  = (const float*)d_in[5];
  const int*   attidx = (const int*)d_in[6];
  const int n_off = in_sizes[5] / 8;

  char* ws = (char*)d_ws;
  short* Xb    = (short*)(ws + WS_XB);
  short* CTX   = (short*)(ws + WS_CTX);
  short* WQT   = (short*)(ws + WS_WQT);
  short* WPT   = (short*)(ws + WS_WPT);
  short* Qw    = (short*)(ws + WS_QW);
  short* Kw    = (short*)(ws + WS_KW);
  short* Vt    = (short*)(ws + WS_VT);
  float* BiasF = (float*)(ws + WS_BIAS);

  k_convert_x<<<14336, 256, 0, stream>>>(X, Xb);
  k_transpose_bf16<<<(1536 * 448 + 255) / 256, 256, 0, stream>>>(qkv_w, WQT, 448, 1536, 1536 * 448);
  k_transpose_bf16<<<(512 * 1024 + 255) / 256, 256, 0, stream>>>(proj_w, WPT, 1024, 448, 512 * 1024);
  k_bias_gather<<<2048, 256, 0, stream>>>(att_b, attidx, BiasF, n_off);

  k_qkv_gemm<<<dim3(512, 12), 256, 0, stream>>>(Xb, WQT, qkv_b, Qw, Kw, Vt);
  k_attn<<<2048, 256, 0, stream>>>(Qw, Kw, Vt, BiasF, CTX);
  k_proj_gemm<<<dim3(512, 4), 256, 0, stream>>>(CTX, WPT, proj_b, (float*)d_out);
}

// Round 3
// 448.766 us; speedup vs baseline: 1.4887x; 1.4887x over previous
//
#include <hip/hip_runtime.h>
#include <hip/hip_bf16.h>
#include <stdint.h>

// ---------------------------------------------------------------------------
// TFEfficientFormerSelfAttention  (B=256, S=256, DIM=448, H=8, KD=32, EKD=128)
// Round 3: bias computed analytically from the 256-entry per-head table
// (off(a,b)=a*16+b), 8-wave attention blocks processing 128 q/phase (V read
// 2x instead of 4x), direct-PV with 32B-chunk stores, QKV GEMM epilogue via
// LDS tile with W-column permutation (coalesced Q/K/Vt writes, SCALE folded
// into W). MFMA fragment layouts (verified m89/m91):
//   A: row=l&15, k=(l>>4)*8+j ; B: col=l&15, k=(l>>4)*8+j ;
//   D: col=l&15, row=(l>>4)*4+r.
// ---------------------------------------------------------------------------

typedef __attribute__((ext_vector_type(4))) float f32x4;
typedef __attribute__((ext_vector_type(8))) short short8;
typedef __attribute__((ext_vector_type(4))) unsigned short u16x4;

#define DEVINL static __device__ __forceinline__

DEVINL unsigned short f2bf(float f) {
  unsigned u = __float_as_uint(f);
  return (unsigned short)((u + 0x7FFFu + ((u >> 16) & 1u)) >> 16);
}
DEVINL float bf2f(short s) {
  return __uint_as_float(((unsigned)(unsigned short)s) << 16);
}

DEVINL void gload_lds16(const void* g, void* l) {
  __builtin_amdgcn_global_load_lds((const __attribute__((address_space(1))) void*)g,
                                   (__attribute__((address_space(3))) void*)l,
                                   16, 0, 0);
}

#define SCALE 0.17677669529663687f

// ---------------- workspace layout (bytes) ----------------
#define WS_XB     ((size_t)0)            // 65536x448 bf16 (56MB); CTX overlays after
#define WS_CTX    ((size_t)0)            // 65536x1024 bf16 (128MB)
#define WS_WQT    ((size_t)134217728)    // 1536x448 bf16 (permuted, scaled)
#define WS_WPT    ((size_t)135593984)    // 512x1024 bf16 (rows 448..511 zero)
#define WS_QW     ((size_t)136642560)    // [2048][256][32] bf16 (pre-scaled)
#define WS_KW     ((size_t)170196992)    // [2048][256][32] bf16
#define WS_VT     ((size_t)203751424)    // [2048][128][264] bf16
#define WS_QKVBP  ((size_t)342163456)    // 1536 f32 (permuted, scaled bias)

// column permutation: n' in [0,1536) -> n in original qkv order
DEVINL int qkv_perm(int np, float* sc) {
  *sc = 1.0f;
  if (np < 512) {
    const int h = np >> 6, c = np & 63;
    if (c < 32) *sc = SCALE;
    return h * 192 + c;
  }
  const int h = (np - 512) >> 7, e = (np - 512) & 127;
  return h * 192 + 64 + e;
}

// ---------------- prep kernels ----------------

__global__ void k_convert_x(const float* __restrict__ x, short* __restrict__ xb) {
  const size_t i = (size_t)blockIdx.x * blockDim.x + threadIdx.x;  // 8 elems each
  const f32x4* src = (const f32x4*)x + i * 2;
  f32x4 a = src[0], b = src[1];
  short8 o;
#pragma unroll
  for (int t = 0; t < 4; ++t) o[t] = (short)f2bf(a[t]);
#pragma unroll
  for (int t = 0; t < 4; ++t) o[4 + t] = (short)f2bf(b[t]);
  ((short8*)xb)[i] = o;
}

__global__ void k_prep_qkvw(const float* __restrict__ w, short* __restrict__ out) {
  const int idx = blockIdx.x * blockDim.x + threadIdx.x;  // [n'][k], 1536*448
  if (idx >= 1536 * 448) return;
  const int np = idx / 448, k = idx - np * 448;
  float sc;
  const int n = qkv_perm(np, &sc);
  out[idx] = (short)f2bf(w[(size_t)k * 1536 + n] * sc);
}

__global__ void k_prep_qkvb(const float* __restrict__ bsrc, float* __restrict__ bdst) {
  const int np = blockIdx.x * blockDim.x + threadIdx.x;
  if (np >= 1536) return;
  float sc;
  const int n = qkv_perm(np, &sc);
  bdst[np] = bsrc[n] * sc;
}

__global__ void k_transpose_bf16(const float* __restrict__ in, short* __restrict__ out,
                                 int K, int N, int total) {
  const int idx = blockIdx.x * blockDim.x + threadIdx.x;
  if (idx >= total) return;
  const int n = idx / K, k = idx - n * K;
  const float v = (n < N) ? in[(size_t)k * N + n] : 0.0f;
  out[idx] = (short)f2bf(v);
}

// ---------------- shared 128x128 GEMM mainloop (m97 structure) ----------------

template <int KSTEPS, int LDA, int LDB>
DEVINL void gemm128_body(const short* __restrict__ A, const short* __restrict__ B,
                         short* Asm, short* Bsm, int m0, int n0, int tid,
                         f32x4 acc[4][4]) {
  const int lane = tid & 63, wave = tid >> 6;
  const int l15 = lane & 15, g = lane >> 4;
  const int wm = wave >> 1, wn = wave & 1;
  const int srow = wave * 32 + (lane >> 2);
  const int scol = (lane & 3) * 8;
  for (int ks = 0; ks < KSTEPS; ++ks) {
    const int k0 = ks * 32;
#pragma unroll
    for (int c = 0; c < 2; ++c) {
      gload_lds16(A + (size_t)(m0 + srow + c * 16) * LDA + k0 + scol,
                  Asm + wave * 1024 + c * 512);
      gload_lds16(B + (size_t)(n0 + srow + c * 16) * LDB + k0 + scol,
                  Bsm + wave * 1024 + c * 512);
    }
    __syncthreads();
    short8 a[4], b[4];
#pragma unroll
    for (int i = 0; i < 4; ++i)
      a[i] = *(const short8*)(Asm + (wm * 64 + i * 16 + l15) * 32 + g * 8);
#pragma unroll
    for (int j = 0; j < 4; ++j)
      b[j] = *(const short8*)(Bsm + (wn * 64 + j * 16 + l15) * 32 + g * 8);
#pragma unroll
    for (int i = 0; i < 4; ++i)
#pragma unroll
      for (int j = 0; j < 4; ++j)
        acc[i][j] = __builtin_amdgcn_mfma_f32_16x16x32_bf16(a[i], b[j], acc[i][j], 0, 0, 0);
    __syncthreads();
  }
}

// ---------------- QKV GEMM: Xb[65536][448] @ W'^T -> Q/K/Vt via LDS tile ----

__global__ __launch_bounds__(256) void k_qkv_gemm(
    const short* __restrict__ Xb, const short* __restrict__ Wt,
    const float* __restrict__ qkvbp,
    short* __restrict__ Qw, short* __restrict__ Kw, short* __restrict__ Vt) {
  __shared__ short Asm[4096], Bsm[4096];
  __shared__ short tile[128 * 136];
  const int tid = threadIdx.x;
  const int m0 = blockIdx.x * 128, n0 = blockIdx.y * 128;
  f32x4 acc[4][4];
#pragma unroll
  for (int i = 0; i < 4; ++i)
#pragma unroll
    for (int j = 0; j < 4; ++j) acc[i][j] = (f32x4){0.f, 0.f, 0.f, 0.f};

  gemm128_body<14, 448, 448>(Xb, Wt, Asm, Bsm, m0, n0, tid, acc);

  const int lane = tid & 63, wave = tid >> 6;
  const int l15 = lane & 15, g = lane >> 4;
  const int wm = wave >> 1, wn = wave & 1;
  const int by = blockIdx.y;
  const int b0 = m0 >> 8, s0 = m0 & 255;

  if (by >= 4) {
    // ---- V block: one head h = by-4, cols = e in [0,128). tile[e][s]. ----
#pragma unroll
    for (int i = 0; i < 4; ++i) {
#pragma unroll
      for (int j = 0; j < 4; ++j) {
        const float bv = qkvbp[n0 + wn * 64 + j * 16 + l15];
        u16x4 pk;
#pragma unroll
        for (int r = 0; r < 4; ++r) pk[r] = f2bf(acc[i][j][r] + bv);
        *(u16x4*)&tile[(wn * 64 + j * 16 + l15) * 136 + wm * 64 + i * 16 + g * 4] = pk;
      }
    }
    __syncthreads();
    const int bh = b0 * 8 + (by - 4);
#pragma unroll
    for (int p = 0; p < 8; ++p) {
      const int er = p * 16 + (tid >> 4);
      const int sc = (tid & 15) * 8;
      short8 v = *(const short8*)&tile[er * 136 + sc];
      *(short8*)(Vt + (size_t)bh * 33792 + er * 264 + s0 + sc) = v;
    }
  } else {
    // ---- QK block: heads h0=2*by, h0+1; 64 cols each (32 Q | 32 K). tile[s][c]. ----
#pragma unroll
    for (int i = 0; i < 4; ++i) {
#pragma unroll
      for (int j = 0; j < 4; ++j) {
        const float bv = qkvbp[n0 + wn * 64 + j * 16 + l15];
#pragma unroll
        for (int r = 0; r < 4; ++r)
          tile[(wm * 64 + i * 16 + g * 4 + r) * 136 + wn * 64 + j * 16 + l15] =
              (short)f2bf(acc[i][j][r] + bv);
      }
    }
    __syncthreads();
    const int h0 = by * 2;
#pragma unroll
    for (int p = 0; p < 8; ++p) {
      const int row = p * 16 + (tid >> 4);
      const int ch = tid & 15;
      short8 v = *(const short8*)&tile[row * 136 + ch * 8];
      const int hl = ch >> 3, cl = (ch & 7) * 8;
      const int bh = b0 * 8 + h0 + hl;
      short* dst = (cl < 32) ? (Qw + (size_t)bh * 8192 + (s0 + row) * 32 + cl)
                             : (Kw + (size_t)bh * 8192 + (s0 + row) * 32 + (cl - 32));
      *(short8*)dst = v;
    }
  }
}

// ---------------- fused attention per (b,h) ----------------
// 512 threads (8 waves), 2 blocks/CU. LDS: P[4][32][264] + rinv + bias table.
// 2 phases x 128 q rows. Per phase: V read exactly once (wave owns 16 e-rows).

__global__ __launch_bounds__(512, 4) void k_attn(
    const short* __restrict__ Qw, const short* __restrict__ Kw,
    const short* __restrict__ Vt, const float* __restrict__ attb, int n_off,
    short* __restrict__ CTX) {
  __shared__ short Ps[4][32 * 264];
  __shared__ float rinv[4][32];
  __shared__ float bias_sm[256];

  const int tid = threadIdx.x, lane = tid & 63, wave = tid >> 6;  // 8 waves
  const int l15 = lane & 15, g = lane >> 4;
  const int bh = blockIdx.x;
  const int b = bh >> 3, h = bh & 7;  // h == bh%8 -> same head per XCD (L2 locality)

  if (tid < 256) bias_sm[tid] = attb[h * n_off + tid];
  __syncthreads();

  const short* Qb = Qw + (size_t)bh * 8192;
  const short* Kb = Kw + (size_t)bh * 8192;
  const short* Vb = Vt + (size_t)bh * 33792;

  for (int ph = 0; ph < 2; ++ph) {
    const int Q0 = ph * 128;

    // ---- scores: wave covers keys [wave*32, wave*32+32) ----
    {
      short8 aq[4][2];
#pragma unroll
      for (int u = 0; u < 4; ++u)
#pragma unroll
        for (int i = 0; i < 2; ++i)
          aq[u][i] = *(const short8*)(Qb + (Q0 + u * 32 + i * 16 + l15) * 32 + g * 8);

#pragma unroll
      for (int fj = 0; fj < 2; ++fj) {
        const int kk0 = wave * 32 + fj * 16;
        const short8 bk = *(const short8*)(Kb + (kk0 + l15) * 32 + g * 8);
        const int kk = kk0 + l15;
        const int kr = kk >> 4, kc = kk & 15;
#pragma unroll
        for (int u = 0; u < 4; ++u) {
#pragma unroll
          for (int i = 0; i < 2; ++i) {
            const int q0 = Q0 + u * 32 + i * 16;
            f32x4 acc;
#pragma unroll
            for (int r = 0; r < 4; ++r) {
              const int qrow = q0 + g * 4 + r;
              const int qr = qrow >> 4, qc = qrow & 15;
              const int a = (qr > kr) ? qr - kr : kr - qr;
              const int bo = (qc > kc) ? qc - kc : kc - qc;
              acc[r] = bias_sm[a * 16 + bo];
            }
            acc = __builtin_amdgcn_mfma_f32_16x16x32_bf16(aq[u][i], bk, acc, 0, 0, 0);
#pragma unroll
            for (int r = 0; r < 4; ++r)
              Ps[u][(i * 16 + g * 4 + r) * 264 + kk] = (short)f2bf(acc[r]);
          }
        }
      }
    }
    __syncthreads();  // B1

    // ---- softmax: 512 threads = 32 rows x 16 parts, per buffer ----
    {
      const int r = tid >> 4, part = tid & 15;
#pragma unroll
      for (int u = 0; u < 4; ++u) {
        short* rowp = &Ps[u][r * 264 + part * 16];
        short8 x0 = ((const short8*)rowp)[0];
        short8 x1 = ((const short8*)rowp)[1];
        float v[16];
#pragma unroll
        for (int t = 0; t < 8; ++t) { v[t] = bf2f(x0[t]); v[8 + t] = bf2f(x1[t]); }
        float mx = v[0];
#pragma unroll
        for (int t = 1; t < 16; ++t) mx = fmaxf(mx, v[t]);
#pragma unroll
        for (int d = 1; d < 16; d <<= 1) mx = fmaxf(mx, __shfl_xor(mx, d));
        float sum = 0.f;
#pragma unroll
        for (int t = 0; t < 16; ++t) { v[t] = __expf(v[t] - mx); sum += v[t]; }
#pragma unroll
        for (int d = 1; d < 16; d <<= 1) sum += __shfl_xor(sum, d);
        short8 o0, o1;
#pragma unroll
        for (int t = 0; t < 8; ++t) { o0[t] = (short)f2bf(v[t]); o1[t] = (short)f2bf(v[8 + t]); }
        ((short8*)rowp)[0] = o0;
        ((short8*)rowp)[1] = o1;
        if (part == 0) rinv[u][r] = 1.0f / sum;
      }
    }
    __syncthreads();  // B2

    // ---- PV direct (A=P rows q, B=V^T cols e): wave owns e [wave*16,+16) ----
    {
      f32x4 cacc[4][2];
#pragma unroll
      for (int u = 0; u < 4; ++u)
#pragma unroll
        for (int qt = 0; qt < 2; ++qt) cacc[u][qt] = (f32x4){0.f, 0.f, 0.f, 0.f};

      const int e = wave * 16 + l15;
#pragma unroll
      for (int ks = 0; ks < 8; ++ks) {
        const short8 bv = *(const short8*)(Vb + e * 264 + ks * 32 + g * 8);
#pragma unroll
        for (int u = 0; u < 4; ++u)
#pragma unroll
          for (int qt = 0; qt < 2; ++qt) {
            const short8 ap = *(const short8*)&Ps[u][(qt * 16 + l15) * 264 + ks * 32 + g * 8];
            cacc[u][qt] = __builtin_amdgcn_mfma_f32_16x16x32_bf16(ap, bv, cacc[u][qt], 0, 0, 0);
          }
      }

#pragma unroll
      for (int u = 0; u < 4; ++u)
#pragma unroll
        for (int qt = 0; qt < 2; ++qt) {
          const int qb = qt * 16 + g * 4;
#pragma unroll
          for (int r = 0; r < 4; ++r) {
            const int q = Q0 + u * 32 + qb + r;
            CTX[((size_t)b * 256 + q) * 1024 + h * 128 + wave * 16 + l15] =
                (short)f2bf(cacc[u][qt][r] * rinv[u][qb + r]);
          }
        }
    }
    __syncthreads();  // B3: Ps free for next phase
  }
}

// ---------------- proj GEMM: CTX[65536][1024] @ WptT -> out f32 ----------------

__global__ __launch_bounds__(256) void k_proj_gemm(
    const short* __restrict__ CTX, const short* __restrict__ Wpt,
    const float* __restrict__ projb, float* __restrict__ out) {
  __shared__ short Asm[4096], Bsm[4096];
  const int tid = threadIdx.x;
  const int m0 = blockIdx.x * 128, n0 = blockIdx.y * 128;
  f32x4 acc[4][4];
#pragma unroll
  for (int i = 0; i < 4; ++i)
#pragma unroll
    for (int j = 0; j < 4; ++j) acc[i][j] = (f32x4){0.f, 0.f, 0.f, 0.f};

  gemm128_body<32, 1024, 1024>(CTX, Wpt, Asm, Bsm, m0, n0, tid, acc);

  const int lane = tid & 63, wave = tid >> 6;
  const int l15 = lane & 15, g = lane >> 4;
  const int wm = wave >> 1, wn = wave & 1;
#pragma unroll
  for (int i = 0; i < 4; ++i) {
    const int mb = m0 + wm * 64 + i * 16 + g * 4;
#pragma unroll
    for (int j = 0; j < 4; ++j) {
      const int n = n0 + wn * 64 + j * 16 + l15;
      if (n < 448) {
        const float bv = projb[n];
#pragma unroll
        for (int r = 0; r < 4; ++r)
          out[(size_t)(mb + r) * 448 + n] = acc[i][j][r] + bv;
      }
    }
  }
}

// ---------------- launch ----------------

extern "C" void kernel_launch(void* const* d_in, const int* in_sizes, int n_in,
                              void* d_out, int out_size, void* d_ws, size_t ws_size,
                              hipStream_t stream) {
  const float* X      = (const float*)d_in[0];
  const float* qkv_w  = (const float*)d_in[1];
  const float* qkv_b  = (const float*)d_in[2];
  const float* proj_w = (const float*)d_in[3];
  const float* proj_b = (const float*)d_in[4];
  const float* att_b  = (const float*)d_in[5];
  const int n_off = in_sizes[5] / 8;

  char* ws = (char*)d_ws;
  short* Xb    = (short*)(ws + WS_XB);
  short* CTX   = (short*)(ws + WS_CTX);
  short* WQT   = (short*)(ws + WS_WQT);
  short* WPT   = (short*)(ws + WS_WPT);
  short* Qw    = (short*)(ws + WS_QW);
  short* Kw    = (short*)(ws + WS_KW);
  short* Vt    = (short*)(ws + WS_VT);
  float* QKVBP = (float*)(ws + WS_QKVBP);

  k_convert_x<<<14336, 256, 0, stream>>>(X, Xb);
  k_prep_qkvw<<<(1536 * 448 + 255) / 256, 256, 0, stream>>>(qkv_w, WQT);
  k_prep_qkvb<<<6, 256, 0, stream>>>(qkv_b, QKVBP);
  k_transpose_bf16<<<(512 * 1024 + 255) / 256, 256, 0, stream>>>(proj_w, WPT, 1024, 448, 512 * 1024);

  k_qkv_gemm<<<dim3(512, 12), 256, 0, stream>>>(Xb, WQT, QKVBP, Qw, Kw, Vt);
  k_attn<<<2048, 512, 0, stream>>>(Qw, Kw, Vt, att_b, n_off, CTX);
  k_proj_gemm<<<dim3(512, 4), 256, 0, stream>>>(CTX, WPT, proj_b, (float*)d_out);
}

// Round 4
// 428.815 us; speedup vs baseline: 1.5580x; 1.0465x over previous
//
#include <hip/hip_runtime.h>
#include <hip/hip_bf16.h>
#include <stdint.h>

// ---------------------------------------------------------------------------
// TFEfficientFormerSelfAttention  (B=256, S=256, DIM=448, H=8, KD=32, EKD=128)
// Round 4: GEMMs rebuilt — n-major grid (A-panel reuse, A fetched once),
// BK=64 K-steps (half the barrier drains), T2 XOR-swizzled LDS (16B-slot
// involution slot^=(row&7): inverse-swizzled gload_lds source + swizzled
// ds_read → 2-way (free) bank access), epilogue tile union'd over staging
// buffers (35KB LDS → 4 blocks/CU). Attention unchanged from round 3.
// MFMA fragment layouts (verified m89/m91):
//   A: row=l&15, k=(l>>4)*8+j ; B: col=l&15, k=(l>>4)*8+j ;
//   D: col=l&15, row=(l>>4)*4+r.
// ---------------------------------------------------------------------------

typedef __attribute__((ext_vector_type(4))) float f32x4;
typedef __attribute__((ext_vector_type(8))) short short8;
typedef __attribute__((ext_vector_type(4))) unsigned short u16x4;

#define DEVINL static __device__ __forceinline__

DEVINL unsigned short f2bf(float f) {
  unsigned u = __float_as_uint(f);
  return (unsigned short)((u + 0x7FFFu + ((u >> 16) & 1u)) >> 16);
}
DEVINL float bf2f(short s) {
  return __uint_as_float(((unsigned)(unsigned short)s) << 16);
}

DEVINL void gload_lds16(const void* g, void* l) {
  __builtin_amdgcn_global_load_lds((const __attribute__((address_space(1))) void*)g,
                                   (__attribute__((address_space(3))) void*)l,
                                   16, 0, 0);
}

#define SCALE 0.17677669529663687f

// ---------------- workspace layout (bytes) ----------------
#define WS_XB     ((size_t)0)            // 65536x448 bf16 (56MB); CTX overlays after
#define WS_CTX    ((size_t)0)            // 65536x1024 bf16 (128MB)
#define WS_WQT    ((size_t)134217728)    // 1536x448 bf16 (permuted, scaled)
#define WS_WPT    ((size_t)135593984)    // 512x1024 bf16 (rows 448..511 zero)
#define WS_QW     ((size_t)136642560)    // [2048][256][32] bf16 (pre-scaled)
#define WS_KW     ((size_t)170196992)    // [2048][256][32] bf16
#define WS_VT     ((size_t)203751424)    // [2048][128][264] bf16
#define WS_QKVBP  ((size_t)342163456)    // 1536 f32 (permuted, scaled bias)

// column permutation: n' in [0,1536) -> n in original qkv order
DEVINL int qkv_perm(int np, float* sc) {
  *sc = 1.0f;
  if (np < 512) {
    const int h = np >> 6, c = np & 63;
    if (c < 32) *sc = SCALE;
    return h * 192 + c;
  }
  const int h = (np - 512) >> 7, e = (np - 512) & 127;
  return h * 192 + 64 + e;
}

// ---------------- prep kernels ----------------

__global__ void k_convert_x(const float* __restrict__ x, short* __restrict__ xb) {
  const size_t i = (size_t)blockIdx.x * blockDim.x + threadIdx.x;  // 8 elems each
  const f32x4* src = (const f32x4*)x + i * 2;
  f32x4 a = src[0], b = src[1];
  short8 o;
#pragma unroll
  for (int t = 0; t < 4; ++t) o[t] = (short)f2bf(a[t]);
#pragma unroll
  for (int t = 0; t < 4; ++t) o[4 + t] = (short)f2bf(b[t]);
  ((short8*)xb)[i] = o;
}

__global__ void k_prep_qkvw(const float* __restrict__ w, short* __restrict__ out) {
  const int idx = blockIdx.x * blockDim.x + threadIdx.x;  // [n'][k], 1536*448
  if (idx >= 1536 * 448) return;
  const int np = idx / 448, k = idx - np * 448;
  float sc;
  const int n = qkv_perm(np, &sc);
  out[idx] = (short)f2bf(w[(size_t)k * 1536 + n] * sc);
}

__global__ void k_prep_qkvb(const float* __restrict__ bsrc, float* __restrict__ bdst) {
  const int np = blockIdx.x * blockDim.x + threadIdx.x;
  if (np >= 1536) return;
  float sc;
  const int n = qkv_perm(np, &sc);
  bdst[np] = bsrc[n] * sc;
}

__global__ void k_transpose_bf16(const float* __restrict__ in, short* __restrict__ out,
                                 int K, int N, int total) {
  const int idx = blockIdx.x * blockDim.x + threadIdx.x;
  if (idx >= total) return;
  const int n = idx / K, k = idx - n * K;
  const float v = (n < N) ? in[(size_t)k * N + n] : 0.0f;
  out[idx] = (short)f2bf(v);
}

// ---------------- 128x128 GEMM mainloop, BK=64, T2-swizzled LDS ----------------
// LDS tiles [128 rows][64 shorts]; 16B slot s of row r holds global slot s^(r&7).
// Staging: wave w, chunk c stages rows [w*32+c*8, +8); lane l -> row +l>>3,
// slot l&7, source col ((l&7)^(l>>3))*8. Reads use slot ((s*4+g)^(l15&7)).

template <int KSTEPS, int LDA, int LDB>
DEVINL void gemm128_body(const short* __restrict__ A, const short* __restrict__ B,
                         short* Asm, short* Bsm, int m0, int n0, int tid,
                         f32x4 acc[4][4]) {
  const int lane = tid & 63, wave = tid >> 6;
  const int l15 = lane & 15, g = lane >> 4;
  const int wm = wave >> 1, wn = wave & 1;
  const int r8 = lane >> 3;                 // 0..7: row within 8-row chunk
  const int scol = (((lane & 7) ^ r8) << 3);  // inverse-swizzled source col (shorts)
  const int wbase = wave * 32;

  for (int ks = 0; ks < KSTEPS; ++ks) {
    const int k0 = ks * 64;
#pragma unroll
    for (int c = 0; c < 4; ++c) {
      const int br = wbase + c * 8;
      gload_lds16(A + (size_t)(m0 + br + r8) * LDA + k0 + scol, Asm + br * 64);
      gload_lds16(B + (size_t)(n0 + br + r8) * LDB + k0 + scol, Bsm + br * 64);
    }
    __syncthreads();
#pragma unroll
    for (int s = 0; s < 2; ++s) {
      const int rslot = (((s * 4 + g) ^ (l15 & 7)) << 3);  // swizzled read (shorts)
      short8 a[4], b[4];
#pragma unroll
      for (int i = 0; i < 4; ++i)
        a[i] = *(const short8*)(Asm + (wm * 64 + i * 16 + l15) * 64 + rslot);
#pragma unroll
      for (int j = 0; j < 4; ++j)
        b[j] = *(const short8*)(Bsm + (wn * 64 + j * 16 + l15) * 64 + rslot);
#pragma unroll
      for (int i = 0; i < 4; ++i)
#pragma unroll
        for (int j = 0; j < 4; ++j)
          acc[i][j] = __builtin_amdgcn_mfma_f32_16x16x32_bf16(a[i], b[j], acc[i][j], 0, 0, 0);
    }
    __syncthreads();
  }
}

// ---------------- QKV GEMM: Xb[65536][448] @ W'^T -> Q/K/Vt via LDS tile ----
// grid (12, 512): x = n-tile (A-panel shared by 12 consecutive blocks).

union QkvSmem {
  struct { short a[128 * 64]; short b[128 * 64]; } ab;
  short tile[128 * 136];
};

__global__ __launch_bounds__(256) void k_qkv_gemm(
    const short* __restrict__ Xb, const short* __restrict__ Wt,
    const float* __restrict__ qkvbp,
    short* __restrict__ Qw, short* __restrict__ Kw, short* __restrict__ Vt) {
  __shared__ __align__(16) QkvSmem sm;
  const int tid = threadIdx.x;
  const int by = blockIdx.x;            // n-tile 0..11
  const int m0 = blockIdx.y * 128, n0 = by * 128;
  f32x4 acc[4][4];
#pragma unroll
  for (int i = 0; i < 4; ++i)
#pragma unroll
    for (int j = 0; j < 4; ++j) acc[i][j] = (f32x4){0.f, 0.f, 0.f, 0.f};

  gemm128_body<7, 448, 448>(Xb, Wt, sm.ab.a, sm.ab.b, m0, n0, tid, acc);

  const int lane = tid & 63, wave = tid >> 6;
  const int l15 = lane & 15, g = lane >> 4;
  const int wm = wave >> 1, wn = wave & 1;
  const int b0 = m0 >> 8, s0 = m0 & 255;

  if (by >= 4) {
    // ---- V block: one head h = by-4, cols = e in [0,128). tile[e][s]. ----
#pragma unroll
    for (int i = 0; i < 4; ++i) {
#pragma unroll
      for (int j = 0; j < 4; ++j) {
        const float bv = qkvbp[n0 + wn * 64 + j * 16 + l15];
        u16x4 pk;
#pragma unroll
        for (int r = 0; r < 4; ++r) pk[r] = f2bf(acc[i][j][r] + bv);
        *(u16x4*)&sm.tile[(wn * 64 + j * 16 + l15) * 136 + wm * 64 + i * 16 + g * 4] = pk;
      }
    }
    __syncthreads();
    const int bh = b0 * 8 + (by - 4);
#pragma unroll
    for (int p = 0; p < 8; ++p) {
      const int er = p * 16 + (tid >> 4);
      const int sc = (tid & 15) * 8;
      short8 v = *(const short8*)&sm.tile[er * 136 + sc];
      *(short8*)(Vt + (size_t)bh * 33792 + er * 264 + s0 + sc) = v;
    }
  } else {
    // ---- QK block: heads h0=2*by, h0+1; 64 cols each (32 Q | 32 K). tile[s][c]. ----
#pragma unroll
    for (int i = 0; i < 4; ++i) {
#pragma unroll
      for (int j = 0; j < 4; ++j) {
        const float bv = qkvbp[n0 + wn * 64 + j * 16 + l15];
#pragma unroll
        for (int r = 0; r < 4; ++r)
          sm.tile[(wm * 64 + i * 16 + g * 4 + r) * 136 + wn * 64 + j * 16 + l15] =
              (short)f2bf(acc[i][j][r] + bv);
      }
    }
    __syncthreads();
    const int h0 = by * 2;
#pragma unroll
    for (int p = 0; p < 8; ++p) {
      const int row = p * 16 + (tid >> 4);
      const int ch = tid & 15;
      short8 v = *(const short8*)&sm.tile[row * 136 + ch * 8];
      const int hl = ch >> 3, cl = (ch & 7) * 8;
      const int bh = b0 * 8 + h0 + hl;
      short* dst = (cl < 32) ? (Qw + (size_t)bh * 8192 + (s0 + row) * 32 + cl)
                             : (Kw + (size_t)bh * 8192 + (s0 + row) * 32 + (cl - 32));
      *(short8*)dst = v;
    }
  }
}

// ---------------- fused attention per (b,h) ----------------
// 512 threads (8 waves), 2 blocks/CU. LDS: P[4][32][264] + rinv + bias table.
// 2 phases x 128 q rows. Per phase: V read exactly once (wave owns 16 e-rows).

__global__ __launch_bounds__(512, 4) void k_attn(
    const short* __restrict__ Qw, const short* __restrict__ Kw,
    const short* __restrict__ Vt, const float* __restrict__ attb, int n_off,
    short* __restrict__ CTX) {
  __shared__ short Ps[4][32 * 264];
  __shared__ float rinv[4][32];
  __shared__ float bias_sm[256];

  const int tid = threadIdx.x, lane = tid & 63, wave = tid >> 6;  // 8 waves
  const int l15 = lane & 15, g = lane >> 4;
  const int bh = blockIdx.x;
  const int b = bh >> 3, h = bh & 7;

  if (tid < 256) bias_sm[tid] = attb[h * n_off + tid];
  __syncthreads();

  const short* Qb = Qw + (size_t)bh * 8192;
  const short* Kb = Kw + (size_t)bh * 8192;
  const short* Vb = Vt + (size_t)bh * 33792;

  for (int ph = 0; ph < 2; ++ph) {
    const int Q0 = ph * 128;

    // ---- scores: wave covers keys [wave*32, wave*32+32) ----
    {
      short8 aq[4][2];
#pragma unroll
      for (int u = 0; u < 4; ++u)
#pragma unroll
        for (int i = 0; i < 2; ++i)
          aq[u][i] = *(const short8*)(Qb + (Q0 + u * 32 + i * 16 + l15) * 32 + g * 8);

#pragma unroll
      for (int fj = 0; fj < 2; ++fj) {
        const int kk0 = wave * 32 + fj * 16;
        const short8 bk = *(const short8*)(Kb + (kk0 + l15) * 32 + g * 8);
        const int kk = kk0 + l15;
        const int kr = kk >> 4, kc = kk & 15;
#pragma unroll
        for (int u = 0; u < 4; ++u) {
#pragma unroll
          for (int i = 0; i < 2; ++i) {
            const int q0 = Q0 + u * 32 + i * 16;
            f32x4 acc;
#pragma unroll
            for (int r = 0; r < 4; ++r) {
              const int qrow = q0 + g * 4 + r;
              const int qr = qrow >> 4, qc = qrow & 15;
              const int a = (qr > kr) ? qr - kr : kr - qr;
              const int bo = (qc > kc) ? qc - kc : kc - qc;
              acc[r] = bias_sm[a * 16 + bo];
            }
            acc = __builtin_amdgcn_mfma_f32_16x16x32_bf16(aq[u][i], bk, acc, 0, 0, 0);
#pragma unroll
            for (int r = 0; r < 4; ++r)
              Ps[u][(i * 16 + g * 4 + r) * 264 + kk] = (short)f2bf(acc[r]);
          }
        }
      }
    }
    __syncthreads();  // B1

    // ---- softmax: 512 threads = 32 rows x 16 parts, per buffer ----
    {
      const int r = tid >> 4, part = tid & 15;
#pragma unroll
      for (int u = 0; u < 4; ++u) {
        short* rowp = &Ps[u][r * 264 + part * 16];
        short8 x0 = ((const short8*)rowp)[0];
        short8 x1 = ((const short8*)rowp)[1];
        float v[16];
#pragma unroll
        for (int t = 0; t < 8; ++t) { v[t] = bf2f(x0[t]); v[8 + t] = bf2f(x1[t]); }
        float mx = v[0];
#pragma unroll
        for (int t = 1; t < 16; ++t) mx = fmaxf(mx, v[t]);
#pragma unroll
        for (int d = 1; d < 16; d <<= 1) mx = fmaxf(mx, __shfl_xor(mx, d));
        float sum = 0.f;
#pragma unroll
        for (int t = 0; t < 16; ++t) { v[t] = __expf(v[t] - mx); sum += v[t]; }
#pragma unroll
        for (int d = 1; d < 16; d <<= 1) sum += __shfl_xor(sum, d);
        short8 o0, o1;
#pragma unroll
        for (int t = 0; t < 8; ++t) { o0[t] = (short)f2bf(v[t]); o1[t] = (short)f2bf(v[8 + t]); }
        ((short8*)rowp)[0] = o0;
        ((short8*)rowp)[1] = o1;
        if (part == 0) rinv[u][r] = 1.0f / sum;
      }
    }
    __syncthreads();  // B2

    // ---- PV direct (A=P rows q, B=V^T cols e): wave owns e [wave*16,+16) ----
    {
      f32x4 cacc[4][2];
#pragma unroll
      for (int u = 0; u < 4; ++u)
#pragma unroll
        for (int qt = 0; qt < 2; ++qt) cacc[u][qt] = (f32x4){0.f, 0.f, 0.f, 0.f};

      const int e = wave * 16 + l15;
#pragma unroll
      for (int ks = 0; ks < 8; ++ks) {
        const short8 bv = *(const short8*)(Vb + e * 264 + ks * 32 + g * 8);
#pragma unroll
        for (int u = 0; u < 4; ++u)
#pragma unroll
          for (int qt = 0; qt < 2; ++qt) {
            const short8 ap = *(const short8*)&Ps[u][(qt * 16 + l15) * 264 + ks * 32 + g * 8];
            cacc[u][qt] = __builtin_amdgcn_mfma_f32_16x16x32_bf16(ap, bv, cacc[u][qt], 0, 0, 0);
          }
      }

#pragma unroll
      for (int u = 0; u < 4; ++u)
#pragma unroll
        for (int qt = 0; qt < 2; ++qt) {
          const int qb = qt * 16 + g * 4;
#pragma unroll
          for (int r = 0; r < 4; ++r) {
            const int q = Q0 + u * 32 + qb + r;
            CTX[((size_t)b * 256 + q) * 1024 + h * 128 + wave * 16 + l15] =
                (short)f2bf(cacc[u][qt][r] * rinv[u][qb + r]);
          }
        }
    }
    __syncthreads();  // B3: Ps free for next phase
  }
}

// ---------------- proj GEMM: CTX[65536][1024] @ WptT -> out f32 ----------------
// grid (4, 512): x = n-tile (CTX panel shared by 4 consecutive blocks).

__global__ __launch_bounds__(256) void k_proj_gemm(
    const short* __restrict__ CTX, const short* __restrict__ Wpt,
    const float* __restrict__ projb, float* __restrict__ out) {
  __shared__ __align__(16) short Asm[128 * 64];
  __shared__ __align__(16) short Bsm[128 * 64];
  const int tid = threadIdx.x;
  const int m0 = blockIdx.y * 128, n0 = blockIdx.x * 128;
  f32x4 acc[4][4];
#pragma unroll
  for (int i = 0; i < 4; ++i)
#pragma unroll
    for (int j = 0; j < 4; ++j) acc[i][j] = (f32x4){0.f, 0.f, 0.f, 0.f};

  gemm128_body<16, 1024, 1024>(CTX, Wpt, Asm, Bsm, m0, n0, tid, acc);

  const int lane = tid & 63, wave = tid >> 6;
  const int l15 = lane & 15, g = lane >> 4;
  const int wm = wave >> 1, wn = wave & 1;
#pragma unroll
  for (int i = 0; i < 4; ++i) {
    const int mb = m0 + wm * 64 + i * 16 + g * 4;
#pragma unroll
    for (int j = 0; j < 4; ++j) {
      const int n = n0 + wn * 64 + j * 16 + l15;
      if (n < 448) {
        const float bv = projb[n];
#pragma unroll
        for (int r = 0; r < 4; ++r)
          out[(size_t)(mb + r) * 448 + n] = acc[i][j][r] + bv;
      }
    }
  }
}

// ---------------- launch ----------------

extern "C" void kernel_launch(void* const* d_in, const int* in_sizes, int n_in,
                              void* d_out, int out_size, void* d_ws, size_t ws_size,
                              hipStream_t stream) {
  const float* X      = (const float*)d_in[0];
  const float* qkv_w  = (const float*)d_in[1];
  const float* qkv_b  = (const float*)d_in[2];
  const float* proj_w = (const float*)d_in[3];
  const float* proj_b = (const float*)d_in[4];
  const float* att_b  = (const float*)d_in[5];
  const int n_off = in_sizes[5] / 8;

  char* ws = (char*)d_ws;
  short* Xb    = (short*)(ws + WS_XB);
  short* CTX   = (short*)(ws + WS_CTX);
  short* WQT   = (short*)(ws + WS_WQT);
  short* WPT   = (short*)(ws + WS_WPT);
  short* Qw    = (short*)(ws + WS_QW);
  short* Kw    = (short*)(ws + WS_KW);
  short* Vt    = (short*)(ws + WS_VT);
  float* QKVBP = (float*)(ws + WS_QKVBP);

  k_convert_x<<<14336, 256, 0, stream>>>(X, Xb);
  k_prep_qkvw<<<(1536 * 448 + 255) / 256, 256, 0, stream>>>(qkv_w, WQT);
  k_prep_qkvb<<<6, 256, 0, stream>>>(qkv_b, QKVBP);
  k_transpose_bf16<<<(512 * 1024 + 255) / 256, 256, 0, stream>>>(proj_w, WPT, 1024, 448, 512 * 1024);

  k_qkv_gemm<<<dim3(12, 512), 256, 0, stream>>>(Xb, WQT, QKVBP, Qw, Kw, Vt);
  k_attn<<<2048, 512, 0, stream>>>(Qw, Kw, Vt, att_b, n_off, CTX);
  k_proj_gemm<<<dim3(4, 512), 256, 0, stream>>>(CTX, WPT, proj_b, (float*)d_out);
}

// Round 5
// 415.292 us; speedup vs baseline: 1.6087x; 1.0326x over previous
//
#include <hip/hip_runtime.h>
#include <hip/hip_bf16.h>
#include <stdint.h>

// ---------------------------------------------------------------------------
// TFEfficientFormerSelfAttention  (B=256, S=256, DIM=448, H=8, KD=32, EKD=128)
// Round 5: T1 XCD-aware chunked block swizzle on both GEMMs (bijective,
// nwg%8==0): all n-tiles of an m-panel + neighboring m-panels land on ONE
// XCD's L2, so A/CTX are fetched from HBM ~once. Everything else unchanged
// from round 4 (BK=64 T2-swizzled LDS, epilogue tile union'd, analytic bias
// attention).
// MFMA fragment layouts (verified m89/m91):
//   A: row=l&15, k=(l>>4)*8+j ; B: col=l&15, k=(l>>4)*8+j ;
//   D: col=l&15, row=(l>>4)*4+r.
// ---------------------------------------------------------------------------

typedef __attribute__((ext_vector_type(4))) float f32x4;
typedef __attribute__((ext_vector_type(8))) short short8;
typedef __attribute__((ext_vector_type(4))) unsigned short u16x4;

#define DEVINL static __device__ __forceinline__

DEVINL unsigned short f2bf(float f) {
  unsigned u = __float_as_uint(f);
  return (unsigned short)((u + 0x7FFFu + ((u >> 16) & 1u)) >> 16);
}
DEVINL float bf2f(short s) {
  return __uint_as_float(((unsigned)(unsigned short)s) << 16);
}

DEVINL void gload_lds16(const void* g, void* l) {
  __builtin_amdgcn_global_load_lds((const __attribute__((address_space(1))) void*)g,
                                   (__attribute__((address_space(3))) void*)l,
                                   16, 0, 0);
}

#define SCALE 0.17677669529663687f

// ---------------- workspace layout (bytes) ----------------
#define WS_XB     ((size_t)0)            // 65536x448 bf16 (56MB); CTX overlays after
#define WS_CTX    ((size_t)0)            // 65536x1024 bf16 (128MB)
#define WS_WQT    ((size_t)134217728)    // 1536x448 bf16 (permuted, scaled)
#define WS_WPT    ((size_t)135593984)    // 512x1024 bf16 (rows 448..511 zero)
#define WS_QW     ((size_t)136642560)    // [2048][256][32] bf16 (pre-scaled)
#define WS_KW     ((size_t)170196992)    // [2048][256][32] bf16
#define WS_VT     ((size_t)203751424)    // [2048][128][264] bf16
#define WS_QKVBP  ((size_t)342163456)    // 1536 f32 (permuted, scaled bias)

// column permutation: n' in [0,1536) -> n in original qkv order
DEVINL int qkv_perm(int np, float* sc) {
  *sc = 1.0f;
  if (np < 512) {
    const int h = np >> 6, c = np & 63;
    if (c < 32) *sc = SCALE;
    return h * 192 + c;
  }
  const int h = (np - 512) >> 7, e = (np - 512) & 127;
  return h * 192 + 64 + e;
}

// ---------------- prep kernels ----------------

__global__ void k_convert_x(const float* __restrict__ x, short* __restrict__ xb) {
  const size_t i = (size_t)blockIdx.x * blockDim.x + threadIdx.x;  // 8 elems each
  const f32x4* src = (const f32x4*)x + i * 2;
  f32x4 a = src[0], b = src[1];
  short8 o;
#pragma unroll
  for (int t = 0; t < 4; ++t) o[t] = (short)f2bf(a[t]);
#pragma unroll
  for (int t = 0; t < 4; ++t) o[4 + t] = (short)f2bf(b[t]);
  ((short8*)xb)[i] = o;
}

__global__ void k_prep_qkvw(const float* __restrict__ w, short* __restrict__ out) {
  const int idx = blockIdx.x * blockDim.x + threadIdx.x;  // [n'][k], 1536*448
  if (idx >= 1536 * 448) return;
  const int np = idx / 448, k = idx - np * 448;
  float sc;
  const int n = qkv_perm(np, &sc);
  out[idx] = (short)f2bf(w[(size_t)k * 1536 + n] * sc);
}

__global__ void k_prep_qkvb(const float* __restrict__ bsrc, float* __restrict__ bdst) {
  const int np = blockIdx.x * blockDim.x + threadIdx.x;
  if (np >= 1536) return;
  float sc;
  const int n = qkv_perm(np, &sc);
  bdst[np] = bsrc[n] * sc;
}

__global__ void k_transpose_bf16(const float* __restrict__ in, short* __restrict__ out,
                                 int K, int N, int total) {
  const int idx = blockIdx.x * blockDim.x + threadIdx.x;
  if (idx >= total) return;
  const int n = idx / K, k = idx - n * K;
  const float v = (n < N) ? in[(size_t)k * N + n] : 0.0f;
  out[idx] = (short)f2bf(v);
}

// ---------------- 128x128 GEMM mainloop, BK=64, T2-swizzled LDS ----------------
// LDS tiles [128 rows][64 shorts]; 16B slot s of row r holds global slot s^(r&7).
// Staging: wave w, chunk c stages rows [w*32+c*8, +8); lane l -> row +l>>3,
// slot l&7, source col ((l&7)^(l>>3))*8. Reads use slot ((s*4+g)^(l15&7)).

template <int KSTEPS, int LDA, int LDB>
DEVINL void gemm128_body(const short* __restrict__ A, const short* __restrict__ B,
                         short* Asm, short* Bsm, int m0, int n0, int tid,
                         f32x4 acc[4][4]) {
  const int lane = tid & 63, wave = tid >> 6;
  const int l15 = lane & 15, g = lane >> 4;
  const int wm = wave >> 1, wn = wave & 1;
  const int r8 = lane >> 3;                 // 0..7: row within 8-row chunk
  const int scol = (((lane & 7) ^ r8) << 3);  // inverse-swizzled source col (shorts)
  const int wbase = wave * 32;

  for (int ks = 0; ks < KSTEPS; ++ks) {
    const int k0 = ks * 64;
#pragma unroll
    for (int c = 0; c < 4; ++c) {
      const int br = wbase + c * 8;
      gload_lds16(A + (size_t)(m0 + br + r8) * LDA + k0 + scol, Asm + br * 64);
      gload_lds16(B + (size_t)(n0 + br + r8) * LDB + k0 + scol, Bsm + br * 64);
    }
    __syncthreads();
#pragma unroll
    for (int s = 0; s < 2; ++s) {
      const int rslot = (((s * 4 + g) ^ (l15 & 7)) << 3);  // swizzled read (shorts)
      short8 a[4], b[4];
#pragma unroll
      for (int i = 0; i < 4; ++i)
        a[i] = *(const short8*)(Asm + (wm * 64 + i * 16 + l15) * 64 + rslot);
#pragma unroll
      for (int j = 0; j < 4; ++j)
        b[j] = *(const short8*)(Bsm + (wn * 64 + j * 16 + l15) * 64 + rslot);
#pragma unroll
      for (int i = 0; i < 4; ++i)
#pragma unroll
        for (int j = 0; j < 4; ++j)
          acc[i][j] = __builtin_amdgcn_mfma_f32_16x16x32_bf16(a[i], b[j], acc[i][j], 0, 0, 0);
    }
    __syncthreads();
  }
}

// ---------------- QKV GEMM: Xb[65536][448] @ W'^T -> Q/K/Vt via LDS tile ----
// 1D grid 6144, XCD-chunked swizzle: each XCD owns 64 consecutive m-panels
// x all 12 n-tiles -> A-panel read once per XCD L2.

union QkvSmem {
  struct { short a[128 * 64]; short b[128 * 64]; } ab;
  short tile[128 * 136];
};

__global__ __launch_bounds__(256) void k_qkv_gemm(
    const short* __restrict__ Xb, const short* __restrict__ Wt,
    const float* __restrict__ qkvbp,
    short* __restrict__ Qw, short* __restrict__ Kw, short* __restrict__ Vt) {
  __shared__ __align__(16) QkvSmem sm;
  const int tid = threadIdx.x;
  // T1 chunked XCD swizzle (nwg=6144, 768/XCD)
  const int l = (blockIdx.x & 7) * 768 + (blockIdx.x >> 3);
  const int mt = l / 12, by = l - mt * 12;  // m-tile 0..511, n-tile 0..11
  const int m0 = mt * 128, n0 = by * 128;
  f32x4 acc[4][4];
#pragma unroll
  for (int i = 0; i < 4; ++i)
#pragma unroll
    for (int j = 0; j < 4; ++j) acc[i][j] = (f32x4){0.f, 0.f, 0.f, 0.f};

  gemm128_body<7, 448, 448>(Xb, Wt, sm.ab.a, sm.ab.b, m0, n0, tid, acc);

  const int lane = tid & 63, wave = tid >> 6;
  const int l15 = lane & 15, g = lane >> 4;
  const int wm = wave >> 1, wn = wave & 1;
  const int b0 = m0 >> 8, s0 = m0 & 255;

  if (by >= 4) {
    // ---- V block: one head h = by-4, cols = e in [0,128). tile[e][s]. ----
#pragma unroll
    for (int i = 0; i < 4; ++i) {
#pragma unroll
      for (int j = 0; j < 4; ++j) {
        const float bv = qkvbp[n0 + wn * 64 + j * 16 + l15];
        u16x4 pk;
#pragma unroll
        for (int r = 0; r < 4; ++r) pk[r] = f2bf(acc[i][j][r] + bv);
        *(u16x4*)&sm.tile[(wn * 64 + j * 16 + l15) * 136 + wm * 64 + i * 16 + g * 4] = pk;
      }
    }
    __syncthreads();
    const int bh = b0 * 8 + (by - 4);
#pragma unroll
    for (int p = 0; p < 8; ++p) {
      const int er = p * 16 + (tid >> 4);
      const int sc = (tid & 15) * 8;
      short8 v = *(const short8*)&sm.tile[er * 136 + sc];
      *(short8*)(Vt + (size_t)bh * 33792 + er * 264 + s0 + sc) = v;
    }
  } else {
    // ---- QK block: heads h0=2*by, h0+1; 64 cols each (32 Q | 32 K). tile[s][c]. ----
#pragma unroll
    for (int i = 0; i < 4; ++i) {
#pragma unroll
      for (int j = 0; j < 4; ++j) {
        const float bv = qkvbp[n0 + wn * 64 + j * 16 + l15];
#pragma unroll
        for (int r = 0; r < 4; ++r)
          sm.tile[(wm * 64 + i * 16 + g * 4 + r) * 136 + wn * 64 + j * 16 + l15] =
              (short)f2bf(acc[i][j][r] + bv);
      }
    }
    __syncthreads();
    const int h0 = by * 2;
#pragma unroll
    for (int p = 0; p < 8; ++p) {
      const int row = p * 16 + (tid >> 4);
      const int ch = tid & 15;
      short8 v = *(const short8*)&sm.tile[row * 136 + ch * 8];
      const int hl = ch >> 3, cl = (ch & 7) * 8;
      const int bh = b0 * 8 + h0 + hl;
      short* dst = (cl < 32) ? (Qw + (size_t)bh * 8192 + (s0 + row) * 32 + cl)
                             : (Kw + (size_t)bh * 8192 + (s0 + row) * 32 + (cl - 32));
      *(short8*)dst = v;
    }
  }
}

// ---------------- fused attention per (b,h) ----------------
// 512 threads (8 waves), 2 blocks/CU. LDS: P[4][32][264] + rinv + bias table.
// 2 phases x 128 q rows. Per phase: V read exactly once (wave owns 16 e-rows).

__global__ __launch_bounds__(512, 4) void k_attn(
    const short* __restrict__ Qw, const short* __restrict__ Kw,
    const short* __restrict__ Vt, const float* __restrict__ attb, int n_off,
    short* __restrict__ CTX) {
  __shared__ short Ps[4][32 * 264];
  __shared__ float rinv[4][32];
  __shared__ float bias_sm[256];

  const int tid = threadIdx.x, lane = tid & 63, wave = tid >> 6;  // 8 waves
  const int l15 = lane & 15, g = lane >> 4;
  const int bh = blockIdx.x;
  const int b = bh >> 3, h = bh & 7;

  if (tid < 256) bias_sm[tid] = attb[h * n_off + tid];
  __syncthreads();

  const short* Qb = Qw + (size_t)bh * 8192;
  const short* Kb = Kw + (size_t)bh * 8192;
  const short* Vb = Vt + (size_t)bh * 33792;

  for (int ph = 0; ph < 2; ++ph) {
    const int Q0 = ph * 128;

    // ---- scores: wave covers keys [wave*32, wave*32+32) ----
    {
      short8 aq[4][2];
#pragma unroll
      for (int u = 0; u < 4; ++u)
#pragma unroll
        for (int i = 0; i < 2; ++i)
          aq[u][i] = *(const short8*)(Qb + (Q0 + u * 32 + i * 16 + l15) * 32 + g * 8);

#pragma unroll
      for (int fj = 0; fj < 2; ++fj) {
        const int kk0 = wave * 32 + fj * 16;
        const short8 bk = *(const short8*)(Kb + (kk0 + l15) * 32 + g * 8);
        const int kk = kk0 + l15;
        const int kr = kk >> 4, kc = kk & 15;
#pragma unroll
        for (int u = 0; u < 4; ++u) {
#pragma unroll
          for (int i = 0; i < 2; ++i) {
            const int q0 = Q0 + u * 32 + i * 16;
            f32x4 acc;
#pragma unroll
            for (int r = 0; r < 4; ++r) {
              const int qrow = q0 + g * 4 + r;
              const int qr = qrow >> 4, qc = qrow & 15;
              const int a = (qr > kr) ? qr - kr : kr - qr;
              const int bo = (qc > kc) ? qc - kc : kc - qc;
              acc[r] = bias_sm[a * 16 + bo];
            }
            acc = __builtin_amdgcn_mfma_f32_16x16x32_bf16(aq[u][i], bk, acc, 0, 0, 0);
#pragma unroll
            for (int r = 0; r < 4; ++r)
              Ps[u][(i * 16 + g * 4 + r) * 264 + kk] = (short)f2bf(acc[r]);
          }
        }
      }
    }
    __syncthreads();  // B1

    // ---- softmax: 512 threads = 32 rows x 16 parts, per buffer ----
    {
      const int r = tid >> 4, part = tid & 15;
#pragma unroll
      for (int u = 0; u < 4; ++u) {
        short* rowp = &Ps[u][r * 264 + part * 16];
        short8 x0 = ((const short8*)rowp)[0];
        short8 x1 = ((const short8*)rowp)[1];
        float v[16];
#pragma unroll
        for (int t = 0; t < 8; ++t) { v[t] = bf2f(x0[t]); v[8 + t] = bf2f(x1[t]); }
        float mx = v[0];
#pragma unroll
        for (int t = 1; t < 16; ++t) mx = fmaxf(mx, v[t]);
#pragma unroll
        for (int d = 1; d < 16; d <<= 1) mx = fmaxf(mx, __shfl_xor(mx, d));
        float sum = 0.f;
#pragma unroll
        for (int t = 0; t < 16; ++t) { v[t] = __expf(v[t] - mx); sum += v[t]; }
#pragma unroll
        for (int d = 1; d < 16; d <<= 1) sum += __shfl_xor(sum, d);
        short8 o0, o1;
#pragma unroll
        for (int t = 0; t < 8; ++t) { o0[t] = (short)f2bf(v[t]); o1[t] = (short)f2bf(v[8 + t]); }
        ((short8*)rowp)[0] = o0;
        ((short8*)rowp)[1] = o1;
        if (part == 0) rinv[u][r] = 1.0f / sum;
      }
    }
    __syncthreads();  // B2

    // ---- PV direct (A=P rows q, B=V^T cols e): wave owns e [wave*16,+16) ----
    {
      f32x4 cacc[4][2];
#pragma unroll
      for (int u = 0; u < 4; ++u)
#pragma unroll
        for (int qt = 0; qt < 2; ++qt) cacc[u][qt] = (f32x4){0.f, 0.f, 0.f, 0.f};

      const int e = wave * 16 + l15;
#pragma unroll
      for (int ks = 0; ks < 8; ++ks) {
        const short8 bv = *(const short8*)(Vb + e * 264 + ks * 32 + g * 8);
#pragma unroll
        for (int u = 0; u < 4; ++u)
#pragma unroll
          for (int qt = 0; qt < 2; ++qt) {
            const short8 ap = *(const short8*)&Ps[u][(qt * 16 + l15) * 264 + ks * 32 + g * 8];
            cacc[u][qt] = __builtin_amdgcn_mfma_f32_16x16x32_bf16(ap, bv, cacc[u][qt], 0, 0, 0);
          }
      }

#pragma unroll
      for (int u = 0; u < 4; ++u)
#pragma unroll
        for (int qt = 0; qt < 2; ++qt) {
          const int qb = qt * 16 + g * 4;
#pragma unroll
          for (int r = 0; r < 4; ++r) {
            const int q = Q0 + u * 32 + qb + r;
            CTX[((size_t)b * 256 + q) * 1024 + h * 128 + wave * 16 + l15] =
                (short)f2bf(cacc[u][qt][r] * rinv[u][qb + r]);
          }
        }
    }
    __syncthreads();  // B3: Ps free for next phase
  }
}

// ---------------- proj GEMM: CTX[65536][1024] @ WptT -> out f32 ----------------
// 1D grid 2048, XCD-chunked swizzle: each XCD owns 64 m-panels x 4 n-tiles.

__global__ __launch_bounds__(256) void k_proj_gemm(
    const short* __restrict__ CTX, const short* __restrict__ Wpt,
    const float* __restrict__ projb, float* __restrict__ out) {
  __shared__ __align__(16) short Asm[128 * 64];
  __shared__ __align__(16) short Bsm[128 * 64];
  const int tid = threadIdx.x;
  // T1 chunked XCD swizzle (nwg=2048, 256/XCD)
  const int l = (blockIdx.x & 7) * 256 + (blockIdx.x >> 3);
  const int mt = l >> 2, nt = l & 3;
  const int m0 = mt * 128, n0 = nt * 128;
  f32x4 acc[4][4];
#pragma unroll
  for (int i = 0; i < 4; ++i)
#pragma unroll
    for (int j = 0; j < 4; ++j) acc[i][j] = (f32x4){0.f, 0.f, 0.f, 0.f};

  gemm128_body<16, 1024, 1024>(CTX, Wpt, Asm, Bsm, m0, n0, tid, acc);

  const int lane = tid & 63, wave = tid >> 6;
  const int l15 = lane & 15, g = lane >> 4;
  const int wm = wave >> 1, wn = wave & 1;
#pragma unroll
  for (int i = 0; i < 4; ++i) {
    const int mb = m0 + wm * 64 + i * 16 + g * 4;
#pragma unroll
    for (int j = 0; j < 4; ++j) {
      const int n = n0 + wn * 64 + j * 16 + l15;
      if (n < 448) {
        const float bv = projb[n];
#pragma unroll
        for (int r = 0; r < 4; ++r)
          out[(size_t)(mb + r) * 448 + n] = acc[i][j][r] + bv;
      }
    }
  }
}

// ---------------- launch ----------------

extern "C" void kernel_launch(void* const* d_in, const int* in_sizes, int n_in,
                              void* d_out, int out_size, void* d_ws, size_t ws_size,
                              hipStream_t stream) {
  const float* X      = (const float*)d_in[0];
  const float* qkv_w  = (const float*)d_in[1];
  const float* qkv_b  = (const float*)d_in[2];
  const float* proj_w = (const float*)d_in[3];
  const float* proj_b = (const float*)d_in[4];
  const float* att_b  = (const float*)d_in[5];
  const int n_off = in_sizes[5] / 8;

  char* ws = (char*)d_ws;
  short* Xb    = (short*)(ws + WS_XB);
  short* CTX   = (short*)(ws + WS_CTX);
  short* WQT   = (short*)(ws + WS_WQT);
  short* WPT   = (short*)(ws + WS_WPT);
  short* Qw    = (short*)(ws + WS_QW);
  short* Kw    = (short*)(ws + WS_KW);
  short* Vt    = (short*)(ws + WS_VT);
  float* QKVBP = (float*)(ws + WS_QKVBP);

  k_convert_x<<<14336, 256, 0, stream>>>(X, Xb);
  k_prep_qkvw<<<(1536 * 448 + 255) / 256, 256, 0, stream>>>(qkv_w, WQT);
  k_prep_qkvb<<<6, 256, 0, stream>>>(qkv_b, QKVBP);
  k_transpose_bf16<<<(512 * 1024 + 255) / 256, 256, 0, stream>>>(proj_w, WPT, 1024, 448, 512 * 1024);

  k_qkv_gemm<<<6144, 256, 0, stream>>>(Xb, WQT, QKVBP, Qw, Kw, Vt);
  k_attn<<<2048, 512, 0, stream>>>(Qw, Kw, Vt, att_b, n_off, CTX);
  k_proj_gemm<<<2048, 256, 0, stream>>>(CTX, WPT, proj_b, (float*)d_out);
}

// Round 6
// 391.736 us; speedup vs baseline: 1.7054x; 1.0601x over previous
//
#include <hip/hip_runtime.h>
#include <hip/hip_bf16.h>
#include <stdint.h>

// ---------------------------------------------------------------------------
// TFEfficientFormerSelfAttention  (B=256, S=256, DIM=448, H=8, KD=32, EKD=128)
// Round 6: 2-phase double-buffered GEMM mainloop (stage next K-tile BEFORE
// computing current -> load latency hidden under 16 ds_read + 32 MFMA; one
// barrier/tile). QK-path epilogue uses operand-SWAPPED MFMA so the D-frag
// reg-span lies along channels -> direct u16x4 global stores (no LDS round
// trip). Keeps round-5 T1 XCD-chunked grid swizzle + T2 LDS XOR swizzle.
// MFMA fragment layouts (verified m89/m91):
//   A: row=l&15, k=(l>>4)*8+j ; B: col=l&15, k=(l>>4)*8+j ;
//   D: col=l&15, row=(l>>4)*4+r.
// ---------------------------------------------------------------------------

typedef __attribute__((ext_vector_type(4))) float f32x4;
typedef __attribute__((ext_vector_type(8))) short short8;
typedef __attribute__((ext_vector_type(4))) unsigned short u16x4;

#define DEVINL static __device__ __forceinline__

DEVINL unsigned short f2bf(float f) {
  unsigned u = __float_as_uint(f);
  return (unsigned short)((u + 0x7FFFu + ((u >> 16) & 1u)) >> 16);
}
DEVINL float bf2f(short s) {
  return __uint_as_float(((unsigned)(unsigned short)s) << 16);
}

DEVINL void gload_lds16(const void* g, void* l) {
  __builtin_amdgcn_global_load_lds((const __attribute__((address_space(1))) void*)g,
                                   (__attribute__((address_space(3))) void*)l,
                                   16, 0, 0);
}

#define SCALE 0.17677669529663687f

// ---------------- workspace layout (bytes) ----------------
#define WS_XB     ((size_t)0)            // 65536x448 bf16 (56MB); CTX overlays after
#define WS_CTX    ((size_t)0)            // 65536x1024 bf16 (128MB)
#define WS_WQT    ((size_t)134217728)    // 1536x448 bf16 (permuted, scaled)
#define WS_WPT    ((size_t)135593984)    // 512x1024 bf16 (rows 448..511 zero)
#define WS_QW     ((size_t)136642560)    // [2048][256][32] bf16 (pre-scaled)
#define WS_KW     ((size_t)170196992)    // [2048][256][32] bf16
#define WS_VT     ((size_t)203751424)    // [2048][128][264] bf16
#define WS_QKVBP  ((size_t)342163456)    // 1536 f32 (permuted, scaled bias)

// column permutation: n' in [0,1536) -> n in original qkv order
DEVINL int qkv_perm(int np, float* sc) {
  *sc = 1.0f;
  if (np < 512) {
    const int h = np >> 6, c = np & 63;
    if (c < 32) *sc = SCALE;
    return h * 192 + c;
  }
  const int h = (np - 512) >> 7, e = (np - 512) & 127;
  return h * 192 + 64 + e;
}

// ---------------- prep kernels ----------------

__global__ void k_convert_x(const float* __restrict__ x, short* __restrict__ xb) {
  const size_t i = (size_t)blockIdx.x * blockDim.x + threadIdx.x;  // 8 elems each
  const f32x4* src = (const f32x4*)x + i * 2;
  f32x4 a = src[0], b = src[1];
  short8 o;
#pragma unroll
  for (int t = 0; t < 4; ++t) o[t] = (short)f2bf(a[t]);
#pragma unroll
  for (int t = 0; t < 4; ++t) o[4 + t] = (short)f2bf(b[t]);
  ((short8*)xb)[i] = o;
}

__global__ void k_prep_qkvw(const float* __restrict__ w, short* __restrict__ out) {
  const int idx = blockIdx.x * blockDim.x + threadIdx.x;  // [n'][k], 1536*448
  if (idx >= 1536 * 448) return;
  const int np = idx / 448, k = idx - np * 448;
  float sc;
  const int n = qkv_perm(np, &sc);
  out[idx] = (short)f2bf(w[(size_t)k * 1536 + n] * sc);
}

__global__ void k_prep_qkvb(const float* __restrict__ bsrc, float* __restrict__ bdst) {
  const int np = blockIdx.x * blockDim.x + threadIdx.x;
  if (np >= 1536) return;
  float sc;
  const int n = qkv_perm(np, &sc);
  bdst[np] = bsrc[n] * sc;
}

__global__ void k_transpose_bf16(const float* __restrict__ in, short* __restrict__ out,
                                 int K, int N, int total) {
  const int idx = blockIdx.x * blockDim.x + threadIdx.x;
  if (idx >= total) return;
  const int n = idx / K, k = idx - n * K;
  const float v = (n < N) ? in[(size_t)k * N + n] : 0.0f;
  out[idx] = (short)f2bf(v);
}

// ------------- 128x128 GEMM mainloop: 2-phase pipeline, BK=64, T2 LDS -------------
// Asm/Bsm: [2][128][64] shorts (double-buffered). 16B slot s of row r holds
// global slot s^(r&7). Stage(next) issued BEFORE compute(cur); the barrier's
// implicit vmcnt(0) drain waits on loads that aged through the compute phase.

template <int KSTEPS, int LDA, int LDB, bool SWAP>
DEVINL void gemm128_pipe(const short* __restrict__ A, const short* __restrict__ B,
                         short* Asm, short* Bsm, int m0, int n0, int tid,
                         f32x4 acc[4][4]) {
  const int lane = tid & 63, wave = tid >> 6;
  const int l15 = lane & 15, g = lane >> 4;
  const int wm = wave >> 1, wn = wave & 1;
  const int r8 = lane >> 3;                  // 0..7: row within 8-row chunk
  const int scol = (((lane & 7) ^ r8) << 3); // inverse-swizzled source col (shorts)
  const int wbase = wave * 32;

  const short* Ab = A + (size_t)(m0 + wbase + r8) * LDA + scol;
  const short* Bb = B + (size_t)(n0 + wbase + r8) * LDB + scol;

  // prologue: stage tile 0 into buffer 0
#pragma unroll
  for (int c = 0; c < 4; ++c) {
    gload_lds16(Ab + (size_t)(c * 8) * LDA, Asm + (wbase + c * 8) * 64);
    gload_lds16(Bb + (size_t)(c * 8) * LDB, Bsm + (wbase + c * 8) * 64);
  }
  __syncthreads();

  for (int ks = 0; ks < KSTEPS; ++ks) {
    const int cur = ks & 1, nxt = cur ^ 1;
    if (ks + 1 < KSTEPS) {   // issue next-tile loads first (async, other buffer)
      const int k0 = (ks + 1) * 64;
#pragma unroll
      for (int c = 0; c < 4; ++c) {
        gload_lds16(Ab + (size_t)(c * 8) * LDA + k0, Asm + nxt * 8192 + (wbase + c * 8) * 64);
        gload_lds16(Bb + (size_t)(c * 8) * LDB + k0, Bsm + nxt * 8192 + (wbase + c * 8) * 64);
      }
    }
#pragma unroll
    for (int s = 0; s < 2; ++s) {
      const int rslot = (((s * 4 + g) ^ (l15 & 7)) << 3);  // swizzled read (shorts)
      short8 a[4], b[4];
#pragma unroll
      for (int i = 0; i < 4; ++i)
        a[i] = *(const short8*)(Asm + cur * 8192 + (wm * 64 + i * 16 + l15) * 64 + rslot);
#pragma unroll
      for (int j = 0; j < 4; ++j)
        b[j] = *(const short8*)(Bsm + cur * 8192 + (wn * 64 + j * 16 + l15) * 64 + rslot);
#pragma unroll
      for (int i = 0; i < 4; ++i)
#pragma unroll
        for (int j = 0; j < 4; ++j)
          acc[i][j] = SWAP
              ? __builtin_amdgcn_mfma_f32_16x16x32_bf16(b[j], a[i], acc[i][j], 0, 0, 0)
              : __builtin_amdgcn_mfma_f32_16x16x32_bf16(a[i], b[j], acc[i][j], 0, 0, 0);
    }
    __syncthreads();  // compiler drains vmcnt(0)+lgkmcnt(0) here: next tile ready
  }
}

// ---------------- QKV GEMM: Xb[65536][448] @ W'^T -> Q/K/Vt ----------------
// 1D grid 6144, XCD-chunked swizzle. V n-tiles (by>=4): normal orientation +
// LDS transpose tile (coalesced Vt rows). QK n-tiles (by<4): SWAPPED MFMA ->
// reg-span along channels -> direct u16x4 stores, no LDS round trip.

union QkvSmem {
  struct { short a[2 * 8192]; short b[2 * 8192]; } ab;   // 64 KB double-buffer
  short tile[128 * 136];                                  // V epilogue transpose
};

__global__ __launch_bounds__(256) void k_qkv_gemm(
    const short* __restrict__ Xb, const short* __restrict__ Wt,
    const float* __restrict__ qkvbp,
    short* __restrict__ Qw, short* __restrict__ Kw, short* __restrict__ Vt) {
  __shared__ __align__(16) QkvSmem sm;
  const int tid = threadIdx.x;
  // T1 chunked XCD swizzle (nwg=6144, 768/XCD)
  const int l = (blockIdx.x & 7) * 768 + (blockIdx.x >> 3);
  const int mt = l / 12, by = l - mt * 12;  // m-tile 0..511, n-tile 0..11
  const int m0 = mt * 128, n0 = by * 128;

  const int lane = tid & 63, wave = tid >> 6;
  const int l15 = lane & 15, g = lane >> 4;
  const int wm = wave >> 1, wn = wave & 1;
  const int b0 = m0 >> 8, s0 = m0 & 255;

  f32x4 acc[4][4];
#pragma unroll
  for (int i = 0; i < 4; ++i)
#pragma unroll
    for (int j = 0; j < 4; ++j) acc[i][j] = (f32x4){0.f, 0.f, 0.f, 0.f};

  if (by >= 4) {
    // ---- V block: one head h = by-4, cols = e in [0,128). tile[e][s]. ----
    gemm128_pipe<7, 448, 448, false>(Xb, Wt, sm.ab.a, sm.ab.b, m0, n0, tid, acc);
#pragma unroll
    for (int i = 0; i < 4; ++i) {
#pragma unroll
      for (int j = 0; j < 4; ++j) {
        const float bv = qkvbp[n0 + wn * 64 + j * 16 + l15];
        u16x4 pk;
#pragma unroll
        for (int r = 0; r < 4; ++r) pk[r] = f2bf(acc[i][j][r] + bv);
        *(u16x4*)&sm.tile[(wn * 64 + j * 16 + l15) * 136 + wm * 64 + i * 16 + g * 4] = pk;
      }
    }
    __syncthreads();
    const int bh = b0 * 8 + (by - 4);
#pragma unroll
    for (int p = 0; p < 8; ++p) {
      const int er = p * 16 + (tid >> 4);
      const int sc = (tid & 15) * 8;
      short8 v = *(const short8*)&sm.tile[er * 136 + sc];
      *(short8*)(Vt + (size_t)bh * 33792 + er * 264 + s0 + sc) = v;
    }
  } else {
    // ---- QK block (SWAPPED): D col=l15 -> s, reg-span -> channel. ----
    gemm128_pipe<7, 448, 448, true>(Xb, Wt, sm.ab.a, sm.ab.b, m0, n0, tid, acc);
#pragma unroll
    for (int i = 0; i < 4; ++i) {
      const int s = s0 + wm * 64 + i * 16 + l15;
#pragma unroll
      for (int j = 0; j < 4; ++j) {
        const int nbase = n0 + wn * 64 + j * 16 + g * 4;  // +r, mult of 4
        const f32x4 bv4 = *(const f32x4*)(qkvbp + nbase);
        u16x4 pk;
#pragma unroll
        for (int r = 0; r < 4; ++r) pk[r] = f2bf(acc[i][j][r] + bv4[r]);
        const int h = (nbase >> 6) & 7, c = nbase & 63;
        const int bh = b0 * 8 + (by << 1) + (nbase >> 6 & 1);
        short* dst = (c < 32) ? (Qw + ((size_t)bh * 256 + s) * 32 + c)
                              : (Kw + ((size_t)bh * 256 + s) * 32 + (c - 32));
        *(u16x4*)dst = pk;
        (void)h;
      }
    }
  }
}

// ---------------- fused attention per (b,h) ----------------
// 512 threads (8 waves), 2 blocks/CU. LDS: P[4][32][264] + rinv + bias table.
// 2 phases x 128 q rows. Per phase: V read exactly once (wave owns 16 e-rows).

__global__ __launch_bounds__(512, 4) void k_attn(
    const short* __restrict__ Qw, const short* __restrict__ Kw,
    const short* __restrict__ Vt, const float* __restrict__ attb, int n_off,
    short* __restrict__ CTX) {
  __shared__ short Ps[4][32 * 264];
  __shared__ float rinv[4][32];
  __shared__ float bias_sm[256];

  const int tid = threadIdx.x, lane = tid & 63, wave = tid >> 6;  // 8 waves
  const int l15 = lane & 15, g = lane >> 4;
  const int bh = blockIdx.x;
  const int b = bh >> 3, h = bh & 7;

  if (tid < 256) bias_sm[tid] = attb[h * n_off + tid];
  __syncthreads();

  const short* Qb = Qw + (size_t)bh * 8192;
  const short* Kb = Kw + (size_t)bh * 8192;
  const short* Vb = Vt + (size_t)bh * 33792;

  for (int ph = 0; ph < 2; ++ph) {
    const int Q0 = ph * 128;

    // ---- scores: wave covers keys [wave*32, wave*32+32) ----
    {
      short8 aq[4][2];
#pragma unroll
      for (int u = 0; u < 4; ++u)
#pragma unroll
        for (int i = 0; i < 2; ++i)
          aq[u][i] = *(const short8*)(Qb + (Q0 + u * 32 + i * 16 + l15) * 32 + g * 8);

#pragma unroll
      for (int fj = 0; fj < 2; ++fj) {
        const int kk0 = wave * 32 + fj * 16;
        const short8 bk = *(const short8*)(Kb + (kk0 + l15) * 32 + g * 8);
        const int kk = kk0 + l15;
        const int kr = kk >> 4, kc = kk & 15;
#pragma unroll
        for (int u = 0; u < 4; ++u) {
#pragma unroll
          for (int i = 0; i < 2; ++i) {
            const int q0 = Q0 + u * 32 + i * 16;
            f32x4 acc;
#pragma unroll
            for (int r = 0; r < 4; ++r) {
              const int qrow = q0 + g * 4 + r;
              const int qr = qrow >> 4, qc = qrow & 15;
              const int a = (qr > kr) ? qr - kr : kr - qr;
              const int bo = (qc > kc) ? qc - kc : kc - qc;
              acc[r] = bias_sm[a * 16 + bo];
            }
            acc = __builtin_amdgcn_mfma_f32_16x16x32_bf16(aq[u][i], bk, acc, 0, 0, 0);
#pragma unroll
            for (int r = 0; r < 4; ++r)
              Ps[u][(i * 16 + g * 4 + r) * 264 + kk] = (short)f2bf(acc[r]);
          }
        }
      }
    }
    __syncthreads();  // B1

    // ---- softmax: 512 threads = 32 rows x 16 parts, per buffer ----
    {
      const int r = tid >> 4, part = tid & 15;
#pragma unroll
      for (int u = 0; u < 4; ++u) {
        short* rowp = &Ps[u][r * 264 + part * 16];
        short8 x0 = ((const short8*)rowp)[0];
        short8 x1 = ((const short8*)rowp)[1];
        float v[16];
#pragma unroll
        for (int t = 0; t < 8; ++t) { v[t] = bf2f(x0[t]); v[8 + t] = bf2f(x1[t]); }
        float mx = v[0];
#pragma unroll
        for (int t = 1; t < 16; ++t) mx = fmaxf(mx, v[t]);
#pragma unroll
        for (int d = 1; d < 16; d <<= 1) mx = fmaxf(mx, __shfl_xor(mx, d));
        float sum = 0.f;
#pragma unroll
        for (int t = 0; t < 16; ++t) { v[t] = __expf(v[t] - mx); sum += v[t]; }
#pragma unroll
        for (int d = 1; d < 16; d <<= 1) sum += __shfl_xor(sum, d);
        short8 o0, o1;
#pragma unroll
        for (int t = 0; t < 8; ++t) { o0[t] = (short)f2bf(v[t]); o1[t] = (short)f2bf(v[8 + t]); }
        ((short8*)rowp)[0] = o0;
        ((short8*)rowp)[1] = o1;
        if (part == 0) rinv[u][r] = 1.0f / sum;
      }
    }
    __syncthreads();  // B2

    // ---- PV direct (A=P rows q, B=V^T cols e): wave owns e [wave*16,+16) ----
    {
      f32x4 cacc[4][2];
#pragma unroll
      for (int u = 0; u < 4; ++u)
#pragma unroll
        for (int qt = 0; qt < 2; ++qt) cacc[u][qt] = (f32x4){0.f, 0.f, 0.f, 0.f};

      const int e = wave * 16 + l15;
#pragma unroll
      for (int ks = 0; ks < 8; ++ks) {
        const short8 bv = *(const short8*)(Vb + e * 264 + ks * 32 + g * 8);
#pragma unroll
        for (int u = 0; u < 4; ++u)
#pragma unroll
          for (int qt = 0; qt < 2; ++qt) {
            const short8 ap = *(const short8*)&Ps[u][(qt * 16 + l15) * 264 + ks * 32 + g * 8];
            cacc[u][qt] = __builtin_amdgcn_mfma_f32_16x16x32_bf16(ap, bv, cacc[u][qt], 0, 0, 0);
          }
      }

#pragma unroll
      for (int u = 0; u < 4; ++u)
#pragma unroll
        for (int qt = 0; qt < 2; ++qt) {
          const int qb = qt * 16 + g * 4;
#pragma unroll
          for (int r = 0; r < 4; ++r) {
            const int q = Q0 + u * 32 + qb + r;
            CTX[((size_t)b * 256 + q) * 1024 + h * 128 + wave * 16 + l15] =
                (short)f2bf(cacc[u][qt][r] * rinv[u][qb + r]);
          }
        }
    }
    __syncthreads();  // B3: Ps free for next phase
  }
}

// ---------------- proj GEMM: CTX[65536][1024] @ WptT -> out f32 ----------------
// 1D grid 2048, XCD-chunked swizzle: each XCD owns 64 m-panels x 4 n-tiles.

__global__ __launch_bounds__(256) void k_proj_gemm(
    const short* __restrict__ CTX, const short* __restrict__ Wpt,
    const float* __restrict__ projb, float* __restrict__ out) {
  __shared__ __align__(16) short Asm[2 * 8192];
  __shared__ __align__(16) short Bsm[2 * 8192];
  const int tid = threadIdx.x;
  // T1 chunked XCD swizzle (nwg=2048, 256/XCD)
  const int l = (blockIdx.x & 7) * 256 + (blockIdx.x >> 3);
  const int mt = l >> 2, nt = l & 3;
  const int m0 = mt * 128, n0 = nt * 128;
  f32x4 acc[4][4];
#pragma unroll
  for (int i = 0; i < 4; ++i)
#pragma unroll
    for (int j = 0; j < 4; ++j) acc[i][j] = (f32x4){0.f, 0.f, 0.f, 0.f};

  gemm128_pipe<16, 1024, 1024, false>(CTX, Wpt, Asm, Bsm, m0, n0, tid, acc);

  const int lane = tid & 63, wave = tid >> 6;
  const int l15 = lane & 15, g = lane >> 4;
  const int wm = wave >> 1, wn = wave & 1;
#pragma unroll
  for (int i = 0; i < 4; ++i) {
    const int mb = m0 + wm * 64 + i * 16 + g * 4;
#pragma unroll
    for (int j = 0; j < 4; ++j) {
      const int n = n0 + wn * 64 + j * 16 + l15;
      if (n < 448) {
        const float bv = projb[n];
#pragma unroll
        for (int r = 0; r < 4; ++r)
          out[(size_t)(mb + r) * 448 + n] = acc[i][j][r] + bv;
      }
    }
  }
}

// ---------------- launch ----------------

extern "C" void kernel_launch(void* const* d_in, const int* in_sizes, int n_in,
                              void* d_out, int out_size, void* d_ws, size_t ws_size,
                              hipStream_t stream) {
  const float* X      = (const float*)d_in[0];
  const float* qkv_w  = (const float*)d_in[1];
  const float* qkv_b  = (const float*)d_in[2];
  const float* proj_w = (const float*)d_in[3];
  const float* proj_b = (const float*)d_in[4];
  const float* att_b  = (const float*)d_in[5];
  const int n_off = in_sizes[5] / 8;

  char* ws = (char*)d_ws;
  short* Xb    = (short*)(ws + WS_XB);
  short* CTX   = (short*)(ws + WS_CTX);
  short* WQT   = (short*)(ws + WS_WQT);
  short* WPT   = (short*)(ws + WS_WPT);
  short* Qw    = (short*)(ws + WS_QW);
  short* Kw    = (short*)(ws + WS_KW);
  short* Vt    = (short*)(ws + WS_VT);
  float* QKVBP = (float*)(ws + WS_QKVBP);

  k_convert_x<<<14336, 256, 0, stream>>>(X, Xb);
  k_prep_qkvw<<<(1536 * 448 + 255) / 256, 256, 0, stream>>>(qkv_w, WQT);
  k_prep_qkvb<<<6, 256, 0, stream>>>(qkv_b, QKVBP);
  k_transpose_bf16<<<(512 * 1024 + 255) / 256, 256, 0, stream>>>(proj_w, WPT, 1024, 448, 512 * 1024);

  k_qkv_gemm<<<6144, 256, 0, stream>>>(Xb, WQT, QKVBP, Qw, Kw, Vt);
  k_attn<<<2048, 512, 0, stream>>>(Qw, Kw, Vt, att_b, n_off, CTX);
  k_proj_gemm<<<2048, 256, 0, stream>>>(CTX, WPT, proj_b, (float*)d_out);
}